// Round 10
// baseline (38.399 us; speedup 1.0000x reference)
//
#include <hip/hip_runtime.h>

// N_TOTAL=10100, D=128, B=2048. F dense-stored, ~33 nnz/row.
// Two kernels, separating streaming from latency-bound work at GRID level:
//  A1 (pure stream): one row per block, 4 waves x quarter-row. Per 64-chunk
//     round: 1 float4 load, cmps, 1 ballot, chunk-granular compaction straight
//     to GLOBAL ws (idx + raw float4). No LDS, no barriers, no atomics -> the
//     whole kernel is a memcpy-shaped gather; measures true gather BW.
//  A2 (latency phase): one row per block, each wave expands its compacted
//     list (wave-uniform broadcast loads, L2-hot), gathers E rows as float2
//     per lane, cross-wave LDS reduce, fused linear epilogue (coalesced W).

#define NTOT 10100
#define NV4  2525     // NTOT/4 exact
#define DIM  128
#define TPB  256
#define NW   4
#define QV4  632      // chunks per wave-quarter (wave 3: 629)
#define WC   40       // per-quarter compacted capacity; quarter nnz ~ Poisson(8.25)

__global__ __launch_bounds__(TPB) void scan_kernel(
    const int*   __restrict__ uids,
    const float* __restrict__ F,
    int*         __restrict__ g_cnt,
    int*         __restrict__ g_idx,
    float4*      __restrict__ g_val)
{
    const int row  = blockIdx.x;
    const int tid  = threadIdx.x;
    const int w    = tid >> 6;
    const int lane = tid & 63;
    const float4* Frow4 = (const float4*)(F + (size_t)uids[row] * NTOT); // 16B-aligned
    const unsigned long long below = (1ULL << lane) - 1ULL;

    const int jbeg = w * QV4;
    const int jend = (w == 3) ? NV4 : (jbeg + QV4);
    int*    my_idx = g_idx + ((size_t)row * NW + w) * WC;
    float4* my_val = g_val + ((size_t)row * NW + w) * WC;

    int  cb  = 0;
    bool ovf = false;
    #pragma unroll
    for (int t = 0; t < 10; ++t) {
        const int j = jbeg + t * 64 + lane;
        float4 v = make_float4(0.f, 0.f, 0.f, 0.f);
        if (t < 9)          v = Frow4[j];        // rounds 0-8 are full for every wave
        else if (j < jend)  v = Frow4[j];        // round 9 predicated (all waves)
        const bool nz = (v.x != 0.0f) | (v.y != 0.0f) | (v.z != 0.0f) | (v.w != 0.0f);
        const unsigned long long m = __ballot(nz);
        if (m) {                                  // wave-uniform; ~56% of rounds
            const int c = __popcll(m);
            if (cb + c <= WC) {                   // wave-uniform guard
                const int p = cb + __popcll(m & below);
                if (nz) { my_idx[p] = j; my_val[p] = v; }  // ~1 lane avg
                cb += c;
            } else {
                ovf = true;
            }
        }
    }
    if (lane == 0) g_cnt[row * NW + w] = ovf ? -1 : cb;
}

__global__ __launch_bounds__(TPB) void agg_lin_kernel(
    const int*    __restrict__ uids,
    const float*  __restrict__ F,
    const float*  __restrict__ E,
    const float*  __restrict__ W,
    const float*  __restrict__ bias,
    const int*    __restrict__ g_cnt,
    const int*    __restrict__ g_idx,
    const float4* __restrict__ g_val,
    float*        __restrict__ out)
{
    __shared__ float s_part[NW][DIM];
    __shared__ float s_agg[DIM];
    __shared__ float s_out[DIM];

    const int row  = blockIdx.x;
    const int tid  = threadIdx.x;
    const int w    = tid >> 6;
    const int lane = tid & 63;
    const int cnt  = g_cnt[row * NW + w];               // wave-uniform
    const int*    my_idx = g_idx + ((size_t)row * NW + w) * WC;
    const float4* my_val = g_val + ((size_t)row * NW + w) * WC;
    const float* Ed = E + 2 * lane;                      // lane owns d = 2l, 2l+1

    float2 acc = make_float2(0.0f, 0.0f);
    if (cnt >= 0) {
        for (int k = 0; k < cnt; ++k) {
            const int    j4 = my_idx[k];                 // broadcast, L2-hot
            const float4 v  = my_val[k];                 // broadcast, L2-hot
            const int n = j4 * 4;
            if (v.x != 0.0f) { float2 e = *(const float2*)(Ed + (size_t)(n    ) * DIM); acc.x += v.x * e.x; acc.y += v.x * e.y; }
            if (v.y != 0.0f) { float2 e = *(const float2*)(Ed + (size_t)(n + 1) * DIM); acc.x += v.y * e.x; acc.y += v.y * e.y; }
            if (v.z != 0.0f) { float2 e = *(const float2*)(Ed + (size_t)(n + 2) * DIM); acc.x += v.z * e.x; acc.y += v.z * e.y; }
            if (v.w != 0.0f) { float2 e = *(const float2*)(Ed + (size_t)(n + 3) * DIM); acc.x += v.w * e.x; acc.y += v.w * e.y; }
        }
    } else {
        // dense fallback over this wave's quarter (never taken in practice)
        const float* Frow = F + (size_t)uids[row] * NTOT;
        const int nbeg = w * QV4 * 4;
        const int nend = (w == 3) ? NTOT : ((w + 1) * QV4 * 4);
        for (int n = nbeg; n < nend; ++n) {
            float fw = Frow[n];
            if (fw != 0.0f) {
                float2 e = *(const float2*)(Ed + (size_t)n * DIM);
                acc.x += fw * e.x; acc.y += fw * e.y;
            }
        }
    }
    *(float2*)&s_part[w][2 * lane] = acc;
    __syncthreads();

    if (tid < DIM)
        s_agg[tid] = s_part[0][tid] + s_part[1][tid] + s_part[2][tid] + s_part[3][tid];
    __syncthreads();

    // out[j] = bias[j] + sum_d agg[d]*W[j][d]; coalesced flat W float4 reads
    const float4* W4 = (const float4*)W;
    #pragma unroll
    for (int q = 0; q < 16; ++q) {
        int i4 = tid + TPB * q;          // flat float4 index 0..4095
        float4 wv = W4[i4];              // fully coalesced, L2-hot
        int j  = i4 >> 5;
        int dd = (i4 & 31) * 4;
        float4 ag = *(const float4*)&s_agg[dd];
        float p = wv.x * ag.x + wv.y * ag.y + wv.z * ag.z + wv.w * ag.w;
        p += __shfl_xor(p, 16);
        p += __shfl_xor(p, 8);
        p += __shfl_xor(p, 4);
        p += __shfl_xor(p, 2);
        p += __shfl_xor(p, 1);
        if ((tid & 31) == 0) s_out[j] = p;
    }
    __syncthreads();
    if (tid < DIM)
        out[(size_t)row * DIM + tid] = bias[tid] + s_out[tid];
}

extern "C" void kernel_launch(void* const* d_in, const int* in_sizes, int n_in,
                              void* d_out, int out_size, void* d_ws, size_t ws_size,
                              hipStream_t stream) {
    const int*   uids = (const int*)  d_in[0];
    const float* F    = (const float*)d_in[1];
    const float* E    = (const float*)d_in[2];
    const float* W    = (const float*)d_in[3];
    const float* bias = (const float*)d_in[4];
    float*       out  = (float*)d_out;

    const int B = in_sizes[0];  // 2048
    // ws carve: val (16B-aligned) | idx | cnt
    char* ws = (char*)d_ws;
    float4* g_val = (float4*)ws;                                  // B*NW*WC*16
    int*    g_idx = (int*)(ws + (size_t)B * NW * WC * 16);        // B*NW*WC*4
    int*    g_cnt = (int*)(ws + (size_t)B * NW * WC * 20);        // B*NW*4

    scan_kernel<<<B, TPB, 0, stream>>>(uids, F, g_cnt, g_idx, g_val);
    agg_lin_kernel<<<B, TPB, 0, stream>>>(uids, F, E, W, bias, g_cnt, g_idx, g_val, out);
}

// Round 11
// 30.888 us; speedup vs baseline: 1.2432x; 1.2432x over previous
//
#include <hip/hip_runtime.h>

// N_TOTAL=10100, D=128, B=2048. F dense-stored, ~33 nnz/row.
// Fused, one row per block, TPB=256 (4 waves). R6 structure, with one change:
//   P1 issues ALL 10 float4 loads per thread back-to-back into registers
//   (clamped addresses, no branches between loads -> MLP=10, ~240KB in
//   flight per CU), THEN runs the compaction machinery on registers.
//   P2: 8 groups x 32 lanes sparse aggregate (float4/lane), x2 unrolled.
//   P3: fused linear, coalesced flat W float4 + 32-lane shuffle reduce.

#define NTOT 10100
#define NV4  2525     // NTOT/4 exact
#define DIM  128
#define CAP  256      // nnz ~ Poisson(32); dense fallback if exceeded
#define TPB  256
#define NLD  10       // ceil(NV4 / TPB)

__global__ __launch_bounds__(TPB) void friendship_kernel(
    const int*   __restrict__ uids,
    const float* __restrict__ F,
    const float* __restrict__ E,
    const float* __restrict__ W,
    const float* __restrict__ bias,
    float*       __restrict__ out)
{
    __shared__ int   s_idx[CAP];
    __shared__ float s_w[CAP];
    __shared__ int   s_cnt;
    __shared__ float s_red[8][DIM];   // 4 KB partials
    __shared__ float s_agg[DIM];
    __shared__ float s_out[DIM];

    const int row = blockIdx.x;
    const int tid = threadIdx.x;
    const int uid = uids[row];
    const float* Frow = F + (size_t)uid * NTOT;
    const float4* Frow4 = (const float4*)Frow;   // uid*40400 % 16 == 0

    if (tid == 0) s_cnt = 0;
    __syncthreads();

    // ---- P1a: issue all NLD loads back-to-back (no branches between) ----
    float4 v[NLD];
    #pragma unroll
    for (int t = 0; t < NLD; ++t) {
        int i  = tid + t * TPB;
        int ic = (i < NV4) ? i : (NV4 - 1);      // clamp keeps address in-bounds
        v[t] = Frow4[ic];                         // unconditional -> hoisted together
    }
    #pragma unroll
    for (int t = 0; t < NLD; ++t) {
        int i = tid + t * TPB;
        if (i >= NV4) v[t] = make_float4(0.f, 0.f, 0.f, 0.f);
    }

    // ---- P1b: compaction on registers (R6-style, one atomic per hit chunk) ----
    #pragma unroll
    for (int t = 0; t < NLD; ++t) {
        int n = (tid + t * TPB) * 4;
        float4 vv = v[t];
        bool ba = vv.x != 0.0f, bb = vv.y != 0.0f, bc = vv.z != 0.0f, bd = vv.w != 0.0f;
        int  m  = (int)ba + (int)bb + (int)bc + (int)bd;
        if (m) {
            int p = atomicAdd(&s_cnt, m);
            if (p + m <= CAP) {
                if (ba) { s_idx[p] = n;     s_w[p] = vv.x; ++p; }
                if (bb) { s_idx[p] = n + 1; s_w[p] = vv.y; ++p; }
                if (bc) { s_idx[p] = n + 2; s_w[p] = vv.z; ++p; }
                if (bd) { s_idx[p] = n + 3; s_w[p] = vv.w; ++p; }
            }
        }
    }
    __syncthreads();

    const int cnt = s_cnt;
    const int g = tid >> 5;    // entry-group 0..7
    const int l = tid & 31;    // lane owns d = 4l..4l+3

    // ---- P2: agg[d] = sum_k w_k * E[n_k][d]; x2 unrolled ----
    float4 acc = make_float4(0.f, 0.f, 0.f, 0.f);
    if (cnt <= CAP) {
        int k = g;
        for (; k + 8 < cnt; k += 16) {
            int   n0 = s_idx[k];     float w0 = s_w[k];
            int   n1 = s_idx[k + 8]; float w1 = s_w[k + 8];
            float4 e0 = *(const float4*)(E + (size_t)n0 * DIM + l * 4);
            float4 e1 = *(const float4*)(E + (size_t)n1 * DIM + l * 4);
            acc.x += w0 * e0.x; acc.y += w0 * e0.y; acc.z += w0 * e0.z; acc.w += w0 * e0.w;
            acc.x += w1 * e1.x; acc.y += w1 * e1.y; acc.z += w1 * e1.z; acc.w += w1 * e1.w;
        }
        for (; k < cnt; k += 8) {
            int   n = s_idx[k];
            float w = s_w[k];
            float4 ev = *(const float4*)(E + (size_t)n * DIM + l * 4);
            acc.x += w * ev.x; acc.y += w * ev.y; acc.z += w * ev.z; acc.w += w * ev.w;
        }
    } else {
        for (int n = g; n < NTOT; n += 8) {   // never taken; correctness net
            float w = Frow[n];
            float4 ev = *(const float4*)(E + (size_t)n * DIM + l * 4);
            acc.x += w * ev.x; acc.y += w * ev.y; acc.z += w * ev.z; acc.w += w * ev.w;
        }
    }
    *(float4*)&s_red[g][l * 4] = acc;
    __syncthreads();

    if (tid < DIM) {
        float sum = 0.0f;
        #pragma unroll
        for (int gg = 0; gg < 8; ++gg) sum += s_red[gg][tid];
        s_agg[tid] = sum;
    }
    __syncthreads();

    // ---- P3: out[j] = bias[j] + sum_d agg[d]*W[j][d]; coalesced W ----
    const float4* W4 = (const float4*)W;
    #pragma unroll
    for (int q = 0; q < 16; ++q) {
        int i4 = tid + TPB * q;          // flat float4 index 0..4095
        float4 wv = W4[i4];              // fully coalesced, L2-hot
        int j  = i4 >> 5;
        int dd = (i4 & 31) * 4;
        float4 ag = *(const float4*)&s_agg[dd];
        float p = wv.x * ag.x + wv.y * ag.y + wv.z * ag.z + wv.w * ag.w;
        p += __shfl_xor(p, 16);
        p += __shfl_xor(p, 8);
        p += __shfl_xor(p, 4);
        p += __shfl_xor(p, 2);
        p += __shfl_xor(p, 1);
        if ((tid & 31) == 0) s_out[j] = p;
    }
    __syncthreads();
    if (tid < DIM)
        out[(size_t)row * DIM + tid] = bias[tid] + s_out[tid];
}

extern "C" void kernel_launch(void* const* d_in, const int* in_sizes, int n_in,
                              void* d_out, int out_size, void* d_ws, size_t ws_size,
                              hipStream_t stream) {
    const int*   uids = (const int*)  d_in[0];
    const float* F    = (const float*)d_in[1];
    const float* E    = (const float*)d_in[2];
    const float* W    = (const float*)d_in[3];
    const float* bias = (const float*)d_in[4];
    float*       out  = (float*)d_out;

    const int B = in_sizes[0];  // 2048
    friendship_kernel<<<B, TPB, 0, stream>>>(uids, F, E, W, bias, out);
}